// Round 8
// baseline (3857.363 us; speedup 1.0000x reference)
//
#include <hip/hip_runtime.h>

typedef unsigned int u32;

#define NNODES 50000
#define NEDGES 800000

// ---------------- degree + inverse ----------------
__global__ __launch_bounds__(256) void deg_hist(const int* __restrict__ dst,
                                                int* __restrict__ deg, int E) {
    int e = blockIdx.x * 256 + threadIdx.x;
    if (e < E) atomicAdd(&deg[dst[e]], 1);
}

__global__ __launch_bounds__(256) void inv_k(const int* __restrict__ deg,
                                             float* __restrict__ inv, int n) {
    int i = blockIdx.x * 256 + threadIdx.x;
    if (i < n) {
        int d = deg[i];
        inv[i] = 1.0f / (float)(d > 0 ? d : 1);
    }
}

// ---------------- epilogue params ----------------
__global__ __launch_bounds__(256) void prep_epi(
    const float* b_in, const float* bs0, const float* g0, const float* bt0,
    const float* m0, const float* v0,
    const float* bs1, const float* g1, const float* bt1, const float* m1, const float* v1,
    const float* br, const float* bc1, const float* bc2,
    float* sc_in, float* sh_in, float* sc0, float* sh0, float* sc1, float* sh1,
    float* sc_r, float* sh_r, float* sc_c1, float* sh_c1, float* sc_c2, float* sh_c2) {
    int t = threadIdx.x;
    if (t < 128) { sc_in[t] = 1.f; sh_in[t] = b_in[t]; }
    if (t < 256) {
        float s = g0[t] * rsqrtf(v0[t] + 1e-5f);
        sc0[t] = s;
        sh0[t] = (bs0[t] - m0[t]) * s + bt0[t];
    }
    if (t < 128) {
        float s = g1[t] * rsqrtf(v1[t] + 1e-5f);
        sc1[t] = s;
        sh1[t] = (bs1[t] - m1[t]) * s + bt1[t];
    }
    if (t < 128) { sc_r[t] = 1.f; sh_r[t] = br[t]; }
    if (t < 64)  { sc_c1[t] = 1.f; sh_c1[t] = bc1[t]; }
    if (t < 16)  { sc_c2[t] = 1.f; sh_c2[t] = bc2[t]; }
}

// ---------------- f32 GEMM, 64x64 tile, 4x4 register tile ----------------
// C[M,N] = act( (A1|A2 split at KA1) @ (B1;B2 split at K1) * scale + shift )
// B row-major [K, ldb] jax [in, out] layout.
template <int RELU>
__global__ __launch_bounds__(256) void gemm64(
    const float* __restrict__ A1, int lda1,
    const float* __restrict__ A2, int lda2, int KA1,
    const float* __restrict__ B1, const float* __restrict__ B2, int K1, int ldb,
    int M, int K,
    const float* __restrict__ scale, const float* __restrict__ shift,
    float* __restrict__ C, int ldc) {
    __shared__ float As[16][68];  // [k][row]
    __shared__ float Bs[16][68];  // [k][col]
    int t = threadIdx.x;
    int cx = t & 15, cy = t >> 4;
    int row0 = blockIdx.y * 64;
    int col0 = blockIdx.x * 64;

    float acc[4][4];
#pragma unroll
    for (int i = 0; i < 4; i++)
#pragma unroll
        for (int j = 0; j < 4; j++) acc[i][j] = 0.f;

    int akk = t & 15;
    int arow = t >> 4;
    int bcol = t & 63;
    int bkk4 = (t >> 6) * 4;

    for (int k0 = 0; k0 < K; k0 += 16) {
#pragma unroll
        for (int i = 0; i < 4; i++) {
            int row = arow + 16 * i;
            int gr = row0 + row;
            if (gr > M - 1) gr = M - 1;
            int gk = k0 + akk;
            float v = (gk < KA1) ? A1[(size_t)gr * lda1 + gk]
                                 : A2[(size_t)gr * lda2 + (gk - KA1)];
            As[akk][row] = v;
        }
#pragma unroll
        for (int i = 0; i < 4; i++) {
            int kk = bkk4 + i;
            int gk = k0 + kk;
            float v = (gk < K1) ? B1[(size_t)gk * ldb + col0 + bcol]
                                : B2[(size_t)(gk - K1) * ldb + col0 + bcol];
            Bs[kk][bcol] = v;
        }
        __syncthreads();
#pragma unroll
        for (int k = 0; k < 16; k++) {
            float a[4], b[4];
#pragma unroll
            for (int i = 0; i < 4; i++) a[i] = As[k][cy * 4 + i];
#pragma unroll
            for (int j = 0; j < 4; j++) b[j] = Bs[k][cx * 4 + j];
#pragma unroll
            for (int i = 0; i < 4; i++)
#pragma unroll
                for (int j = 0; j < 4; j++) acc[i][j] += a[i] * b[j];
        }
        __syncthreads();
    }

#pragma unroll
    for (int i = 0; i < 4; i++) {
        int row = row0 + cy * 4 + i;
        if (row < M) {
#pragma unroll
            for (int j = 0; j < 4; j++) {
                int col = col0 + cx * 4 + j;
                float v = acc[i][j] * scale[col] + shift[col];
                if (RELU) v = fmaxf(v, 0.f);
                C[(size_t)row * ldc + col] = v;
            }
        }
    }
}

// ---------------- small-N f32 GEMM (N=16), f32 output ----------------
// B row-major [K,16] jax layout. M multiple of 16.
__global__ void gemm16_f32(
    const float* __restrict__ A, int lda,
    const float* __restrict__ B, int ldb,
    int K,
    const float* __restrict__ scale, const float* __restrict__ shift,
    float* __restrict__ C) {
    __shared__ float As[16][17];
    __shared__ float Bs[16][17];
    int tx = threadIdx.x, ty = threadIdx.y;
    int row = blockIdx.y * 16 + ty;
    float acc = 0.f;
    for (int k0 = 0; k0 < K; k0 += 16) {
        As[ty][tx] = A[(size_t)row * lda + k0 + tx];
        Bs[ty][tx] = B[(size_t)(k0 + ty) * ldb + tx];
        __syncthreads();
#pragma unroll
        for (int k = 0; k < 16; k++) acc += As[ty][k] * Bs[k][tx];
        __syncthreads();
    }
    float v = acc * scale[tx] + shift[tx];
    C[(size_t)row * 16 + tx] = v;
}

// ---------------- edge-parallel scatter aggregation (atomic f32) ----------
template <int F>
__global__ __launch_bounds__(256) void agg_scatter(
    const int* __restrict__ src, const int* __restrict__ dst,
    const float* __restrict__ H, int ldh,
    float* __restrict__ D, int ldd, int E) {
    int e = blockIdx.x * 4 + (threadIdx.x >> 6);
    if (e >= E) return;
    int lane = threadIdx.x & 63;
    int s = src[e], d = dst[e];
    if constexpr (F == 128) {
        float2 v = *(const float2*)(H + (size_t)s * ldh + lane * 2);
        float* p = D + (size_t)d * ldd + lane * 2;
        atomicAdd(p, v.x);
        atomicAdd(p + 1, v.y);
    } else {
        float4 v = *(const float4*)(H + (size_t)s * ldh + lane * 4);
        float* p = D + (size_t)d * ldd + lane * 4;
        atomicAdd(p, v.x);
        atomicAdd(p + 1, v.y);
        atomicAdd(p + 2, v.z);
        atomicAdd(p + 3, v.w);
    }
}

// ---------------- row scaling by inv_deg ----------------
template <int LOG>
__global__ __launch_bounds__(256) void scale_rows(
    float* __restrict__ X, int ld, int cofs,
    const float* __restrict__ inv, int n) {
    int tid = blockIdx.x * 256 + threadIdx.x;
    int v = tid >> LOG;
    int f = (tid & ((1 << LOG) - 1)) * 4;
    if (v >= n) return;
    float s = inv[v];
    float4* p = (float4*)(X + (size_t)v * ld + cofs + f);
    float4 x = *p;
    x.x *= s; x.y *= s; x.z *= s; x.w *= s;
    *p = x;
}

// ---------------- launch ----------------
extern "C" void kernel_launch(void* const* d_in, const int* in_sizes, int n_in,
                              void* d_out, int out_size, void* d_ws, size_t ws_size,
                              hipStream_t stream) {
    const int N = NNODES, E = NEDGES;
    const float* features = (const float*)d_in[0];
    const int* src = (const int*)d_in[1];
    const int* dst = (const int*)d_in[2];
    const float* W_in = (const float*)d_in[3];   // [128,128] jax [in,out]
    const float* Ws0 = (const float*)d_in[5];    // [128,256]
    const float* Wn0 = (const float*)d_in[6];    // [128,256]
    const float* Ws1 = (const float*)d_in[12];   // [256,128]
    const float* Wn1 = (const float*)d_in[13];   // [256,128]
    const float* Wr  = (const float*)d_in[19];   // [256,128]
    const float* Wc1 = (const float*)d_in[21];   // [128,64]
    const float* Wc2 = (const float*)d_in[23];   // [64,16]
    float* out = (float*)d_out;                  // f32! (R7 probe: harness reads f32)

    char* w = (char*)d_ws;
    auto alloc = [&](size_t bytes) -> char* {
        char* p = w;
        w += (bytes + 255) & ~(size_t)255;
        return p;
    };
    int*   deg   = (int*)alloc((size_t)N * 4);
    float* inv   = (float*)alloc((size_t)N * 4);
    float* hcat0 = (float*)alloc((size_t)N * 256 * 4);  // [h0 | n0]
    float* hcat1 = (float*)alloc((size_t)N * 512 * 4);  // [h1 | n1]; later hf, tc
    float* h2    = (float*)alloc((size_t)N * 128 * 4);
    float* sc_in = (float*)alloc(128 * 4); float* sh_in = (float*)alloc(128 * 4);
    float* sc0   = (float*)alloc(256 * 4); float* sh0   = (float*)alloc(256 * 4);
    float* sc1   = (float*)alloc(128 * 4); float* sh1   = (float*)alloc(128 * 4);
    float* sc_r  = (float*)alloc(128 * 4); float* sh_r  = (float*)alloc(128 * 4);
    float* sc_c1 = (float*)alloc(64 * 4);  float* sh_c1 = (float*)alloc(64 * 4);
    float* sc_c2 = (float*)alloc(16 * 4);  float* sh_c2 = (float*)alloc(16 * 4);
    float* hf = hcat1;                        // hcat1 dead after h2
    float* tc = hcat1 + (size_t)N * 128;

    hipMemsetAsync(deg, 0, (size_t)N * 4, stream);
    hipMemsetAsync(hcat0, 0, (size_t)N * 256 * 4, stream);
    hipMemsetAsync(hcat1, 0, (size_t)N * 512 * 4, stream);
    prep_epi<<<1, 256, 0, stream>>>((const float*)d_in[4], (const float*)d_in[7],
                                    (const float*)d_in[8], (const float*)d_in[9],
                                    (const float*)d_in[10], (const float*)d_in[11],
                                    (const float*)d_in[14], (const float*)d_in[15],
                                    (const float*)d_in[16], (const float*)d_in[17],
                                    (const float*)d_in[18], (const float*)d_in[20],
                                    (const float*)d_in[22], (const float*)d_in[24],
                                    sc_in, sh_in, sc0, sh0, sc1, sh1,
                                    sc_r, sh_r, sc_c1, sh_c1, sc_c2, sh_c2);
    deg_hist<<<(E + 255) / 256, 256, 0, stream>>>(dst, deg, E);
    inv_k<<<(N + 255) / 256, 256, 0, stream>>>(deg, inv, N);

    int gby = (N + 63) / 64;
    // h0 = relu(features @ W_in + b_in) -> hcat0[:,0:128]
    gemm64<1><<<dim3(2, gby), 256, 0, stream>>>(
        features, 128, features, 128, 128,
        W_in, W_in, 128, 128, N, 128, sc_in, sh_in, hcat0, 256);
    // n0 = mean-neighbor(h0) -> hcat0[:,128:256]
    agg_scatter<128><<<(E + 3) / 4, 256, 0, stream>>>(src, dst, hcat0, 256,
                                                      hcat0 + 128, 256, E);
    scale_rows<5><<<(N * 32 + 255) / 256, 256, 0, stream>>>(hcat0, 256, 128, inv, N);
    // h1 = relu(bn0([h0|n0] @ [Ws0;Wn0] + bs0)) -> hcat1[:,0:256]
    gemm64<1><<<dim3(4, gby), 256, 0, stream>>>(
        hcat0, 256, hcat0, 256, 256,
        Ws0, Wn0, 128, 256, N, 256, sc0, sh0, hcat1, 512);
    // n1 = mean-neighbor(h1) -> hcat1[:,256:512]
    agg_scatter<256><<<(E + 3) / 4, 256, 0, stream>>>(src, dst, hcat1, 512,
                                                      hcat1 + 256, 512, E);
    scale_rows<6><<<(N * 64 + 255) / 256, 256, 0, stream>>>(hcat1, 512, 256, inv, N);
    // h2 = relu(bn1([h1|n1] @ [Ws1;Wn1] + bs1))
    gemm64<1><<<dim3(2, gby), 256, 0, stream>>>(
        hcat1, 512, hcat1, 512, 512,
        Ws1, Wn1, 256, 128, N, 512, sc1, sh1, h2, 128);
    // hf = relu([h0|h2] @ Wr + br)
    gemm64<1><<<dim3(2, gby), 256, 0, stream>>>(
        hcat0, 256, h2, 128, 128,
        Wr, Wr, 256, 128, N, 256, sc_r, sh_r, hf, 128);
    // tc = relu(hf @ Wc1 + bc1)
    gemm64<1><<<dim3(1, gby), 256, 0, stream>>>(
        hf, 128, hf, 128, 128,
        Wc1, Wc1, 128, 64, N, 128, sc_c1, sh_c1, tc, 64);
    // out = tc @ Wc2 + bc2 (f32)
    gemm16_f32<<<dim3(1, N / 16), dim3(16, 16), 0, stream>>>(
        tc, 64, Wc2, 16, 64, sc_c2, sh_c2, out);
}

// Round 9
// 852.504 us; speedup vs baseline: 4.5247x; 4.5247x over previous
//
#include <hip/hip_runtime.h>

#define NNODES 50000
#define NEDGES 800000

// ---------------- CSR build ----------------
__global__ __launch_bounds__(256) void deg_hist(const int* __restrict__ dst,
                                                int* __restrict__ deg, int E) {
    int e = blockIdx.x * 256 + threadIdx.x;
    if (e < E) atomicAdd(&deg[dst[e]], 1);
}

__global__ __launch_bounds__(1024) void scan_csr(const int* __restrict__ deg,
                                                 int* __restrict__ off,
                                                 int* __restrict__ cursor,
                                                 float* __restrict__ inv_deg, int n) {
    __shared__ int lds[1024];
    int t = threadIdx.x;
    int ch = (n + 1023) >> 10;
    int i0 = t * ch, i1 = i0 + ch;
    if (i0 > n) i0 = n;
    if (i1 > n) i1 = n;
    int s = 0;
    for (int i = i0; i < i1; i++) s += deg[i];
    lds[t] = s;
    __syncthreads();
    for (int o = 1; o < 1024; o <<= 1) {
        int v = (t >= o) ? lds[t - o] : 0;
        __syncthreads();
        lds[t] += v;
        __syncthreads();
    }
    int run = (t == 0) ? 0 : lds[t - 1];
    for (int i = i0; i < i1; i++) {
        int d = deg[i];
        off[i] = run;
        cursor[i] = run;
        inv_deg[i] = 1.0f / (float)(d > 0 ? d : 1);
        run += d;
    }
    if (t == 1023) off[n] = lds[1023];
}

__global__ __launch_bounds__(256) void csr_fill(const int* __restrict__ src,
                                                const int* __restrict__ dst,
                                                int* __restrict__ cursor,
                                                int* __restrict__ csr, int E) {
    int e = blockIdx.x * 256 + threadIdx.x;
    if (e < E) {
        int p = atomicAdd(&cursor[dst[e]], 1);
        csr[p] = src[e];
    }
}

// ---------------- epilogue params ----------------
__global__ __launch_bounds__(256) void prep_epi(
    const float* b_in, const float* bs0, const float* g0, const float* bt0,
    const float* m0, const float* v0,
    const float* bs1, const float* g1, const float* bt1, const float* m1, const float* v1,
    const float* br, const float* bc1, const float* bc2,
    float* sc_in, float* sh_in, float* sc0, float* sh0, float* sc1, float* sh1,
    float* sc_r, float* sh_r, float* sc_c1, float* sh_c1, float* sc_c2, float* sh_c2) {
    int t = threadIdx.x;
    if (t < 128) { sc_in[t] = 1.f; sh_in[t] = b_in[t]; }
    if (t < 256) {
        float s = g0[t] * rsqrtf(v0[t] + 1e-5f);
        sc0[t] = s;
        sh0[t] = (bs0[t] - m0[t]) * s + bt0[t];
    }
    if (t < 128) {
        float s = g1[t] * rsqrtf(v1[t] + 1e-5f);
        sc1[t] = s;
        sh1[t] = (bs1[t] - m1[t]) * s + bt1[t];
    }
    if (t < 128) { sc_r[t] = 1.f; sh_r[t] = br[t]; }
    if (t < 64)  { sc_c1[t] = 1.f; sh_c1[t] = bc1[t]; }
    if (t < 16)  { sc_c2[t] = 1.f; sh_c2[t] = bc2[t]; }
}

// ---------------- f32 GEMM, 64x64 tile, 4x4 register tile ----------------
template <int RELU>
__global__ __launch_bounds__(256) void gemm64(
    const float* __restrict__ A1, int lda1,
    const float* __restrict__ A2, int lda2, int KA1,
    const float* __restrict__ B1, const float* __restrict__ B2, int K1, int ldb,
    int M, int K,
    const float* __restrict__ scale, const float* __restrict__ shift,
    float* __restrict__ C, int ldc) {
    __shared__ float As[16][68];  // [k][row]
    __shared__ float Bs[16][68];  // [k][col]
    int t = threadIdx.x;
    int cx = t & 15, cy = t >> 4;
    int row0 = blockIdx.y * 64;
    int col0 = blockIdx.x * 64;

    float acc[4][4];
#pragma unroll
    for (int i = 0; i < 4; i++)
#pragma unroll
        for (int j = 0; j < 4; j++) acc[i][j] = 0.f;

    int akk = t & 15;
    int arow = t >> 4;
    int bcol = t & 63;
    int bkk4 = (t >> 6) * 4;

    for (int k0 = 0; k0 < K; k0 += 16) {
#pragma unroll
        for (int i = 0; i < 4; i++) {
            int row = arow + 16 * i;
            int gr = row0 + row;
            if (gr > M - 1) gr = M - 1;
            int gk = k0 + akk;
            float v = (gk < KA1) ? A1[(size_t)gr * lda1 + gk]
                                 : A2[(size_t)gr * lda2 + (gk - KA1)];
            As[akk][row] = v;
        }
#pragma unroll
        for (int i = 0; i < 4; i++) {
            int kk = bkk4 + i;
            int gk = k0 + kk;
            float v = (gk < K1) ? B1[(size_t)gk * ldb + col0 + bcol]
                                : B2[(size_t)(gk - K1) * ldb + col0 + bcol];
            Bs[kk][bcol] = v;
        }
        __syncthreads();
#pragma unroll
        for (int k = 0; k < 16; k++) {
            float a[4], b[4];
#pragma unroll
            for (int i = 0; i < 4; i++) a[i] = As[k][cy * 4 + i];
#pragma unroll
            for (int j = 0; j < 4; j++) b[j] = Bs[k][cx * 4 + j];
#pragma unroll
            for (int i = 0; i < 4; i++)
#pragma unroll
                for (int j = 0; j < 4; j++) acc[i][j] += a[i] * b[j];
        }
        __syncthreads();
    }

#pragma unroll
    for (int i = 0; i < 4; i++) {
        int row = row0 + cy * 4 + i;
        if (row < M) {
#pragma unroll
            for (int j = 0; j < 4; j++) {
                int col = col0 + cx * 4 + j;
                float v = acc[i][j] * scale[col] + shift[col];
                if (RELU) v = fmaxf(v, 0.f);
                C[(size_t)row * ldc + col] = v;
            }
        }
    }
}

// ---------------- small-N f32 GEMM (N=16), f32 output ----------------
__global__ void gemm16_f32(
    const float* __restrict__ A, int lda,
    const float* __restrict__ B, int ldb,
    int K,
    const float* __restrict__ scale, const float* __restrict__ shift,
    float* __restrict__ C) {
    __shared__ float As[16][17];
    __shared__ float Bs[16][17];
    int tx = threadIdx.x, ty = threadIdx.y;
    int row = blockIdx.y * 16 + ty;
    float acc = 0.f;
    for (int k0 = 0; k0 < K; k0 += 16) {
        As[ty][tx] = A[(size_t)row * lda + k0 + tx];
        Bs[ty][tx] = B[(size_t)(k0 + ty) * ldb + tx];
        __syncthreads();
#pragma unroll
        for (int k = 0; k < 16; k++) acc += As[ty][k] * Bs[k][tx];
        __syncthreads();
    }
    float v = acc * scale[tx] + shift[tx];
    C[(size_t)row * 16 + tx] = v;
}

// ---------------- CSR node-parallel gather mean (1 wave per node) ---------
// D[v] = inv_deg[v] * sum_{u in N(v)} H[u];  fused mean, no atomics.
template <int F>
__global__ __launch_bounds__(256) void agg_gather(
    const int* __restrict__ off, const int* __restrict__ csr,
    const float* __restrict__ inv_deg,
    const float* __restrict__ H, int ldh,
    float* __restrict__ D, int ldd, int n) {
    int v = blockIdx.x * 4 + (threadIdx.x >> 6);
    if (v >= n) return;
    int lane = threadIdx.x & 63;
    int e0 = off[v], e1 = off[v + 1];
    float s = inv_deg[v];
    if constexpr (F == 128) {
        float ax = 0.f, ay = 0.f;
        for (int e = e0; e < e1; e++) {
            int u = csr[e];
            float2 w = *(const float2*)(H + (size_t)u * ldh + lane * 2);
            ax += w.x; ay += w.y;
        }
        float2 o = make_float2(ax * s, ay * s);
        *(float2*)(D + (size_t)v * ldd + lane * 2) = o;
    } else {
        float ax = 0.f, ay = 0.f, az = 0.f, aw = 0.f;
        for (int e = e0; e < e1; e++) {
            int u = csr[e];
            float4 w = *(const float4*)(H + (size_t)u * ldh + lane * 4);
            ax += w.x; ay += w.y; az += w.z; aw += w.w;
        }
        float4 o = make_float4(ax * s, ay * s, az * s, aw * s);
        *(float4*)(D + (size_t)v * ldd + lane * 4) = o;
    }
}

// ---------------- launch ----------------
extern "C" void kernel_launch(void* const* d_in, const int* in_sizes, int n_in,
                              void* d_out, int out_size, void* d_ws, size_t ws_size,
                              hipStream_t stream) {
    const int N = NNODES, E = NEDGES;
    const float* features = (const float*)d_in[0];
    const int* src = (const int*)d_in[1];
    const int* dst = (const int*)d_in[2];
    const float* W_in = (const float*)d_in[3];   // [128,128] jax [in,out]
    const float* Ws0 = (const float*)d_in[5];    // [128,256]
    const float* Wn0 = (const float*)d_in[6];    // [128,256]
    const float* Ws1 = (const float*)d_in[12];   // [256,128]
    const float* Wn1 = (const float*)d_in[13];   // [256,128]
    const float* Wr  = (const float*)d_in[19];   // [256,128]
    const float* Wc1 = (const float*)d_in[21];   // [128,64]
    const float* Wc2 = (const float*)d_in[23];   // [64,16]
    float* out = (float*)d_out;                  // f32 output

    char* w = (char*)d_ws;
    auto alloc = [&](size_t bytes) -> char* {
        char* p = w;
        w += (bytes + 255) & ~(size_t)255;
        return p;
    };
    int*   deg    = (int*)alloc((size_t)N * 4);
    int*   off    = (int*)alloc((size_t)(N + 1) * 4);
    int*   cursor = (int*)alloc((size_t)N * 4);
    int*   csr    = (int*)alloc((size_t)E * 4);
    float* inv    = (float*)alloc((size_t)N * 4);
    float* hcat0  = (float*)alloc((size_t)N * 256 * 4);  // [h0 | n0]
    float* hcat1  = (float*)alloc((size_t)N * 512 * 4);  // [h1 | n1]; later hf, tc
    float* h2     = (float*)alloc((size_t)N * 128 * 4);
    float* sc_in = (float*)alloc(128 * 4); float* sh_in = (float*)alloc(128 * 4);
    float* sc0   = (float*)alloc(256 * 4); float* sh0   = (float*)alloc(256 * 4);
    float* sc1   = (float*)alloc(128 * 4); float* sh1   = (float*)alloc(128 * 4);
    float* sc_r  = (float*)alloc(128 * 4); float* sh_r  = (float*)alloc(128 * 4);
    float* sc_c1 = (float*)alloc(64 * 4);  float* sh_c1 = (float*)alloc(64 * 4);
    float* sc_c2 = (float*)alloc(16 * 4);  float* sh_c2 = (float*)alloc(16 * 4);
    float* hf = hcat1;                        // hcat1 dead after h2
    float* tc = hcat1 + (size_t)N * 128;

    hipMemsetAsync(deg, 0, (size_t)N * 4, stream);
    prep_epi<<<1, 256, 0, stream>>>((const float*)d_in[4], (const float*)d_in[7],
                                    (const float*)d_in[8], (const float*)d_in[9],
                                    (const float*)d_in[10], (const float*)d_in[11],
                                    (const float*)d_in[14], (const float*)d_in[15],
                                    (const float*)d_in[16], (const float*)d_in[17],
                                    (const float*)d_in[18], (const float*)d_in[20],
                                    (const float*)d_in[22], (const float*)d_in[24],
                                    sc_in, sh_in, sc0, sh0, sc1, sh1,
                                    sc_r, sh_r, sc_c1, sh_c1, sc_c2, sh_c2);
    deg_hist<<<(E + 255) / 256, 256, 0, stream>>>(dst, deg, E);
    scan_csr<<<1, 1024, 0, stream>>>(deg, off, cursor, inv, N);
    csr_fill<<<(E + 255) / 256, 256, 0, stream>>>(src, dst, cursor, csr, E);

    int gby = (N + 63) / 64;
    // h0 = relu(features @ W_in + b_in) -> hcat0[:,0:128]
    gemm64<1><<<dim3(2, gby), 256, 0, stream>>>(
        features, 128, features, 128, 128,
        W_in, W_in, 128, 128, N, 128, sc_in, sh_in, hcat0, 256);
    // n0 = mean-neighbor(h0) -> hcat0[:,128:256]   (CSR gather, no atomics)
    agg_gather<128><<<(N + 3) / 4, 256, 0, stream>>>(off, csr, inv,
                                                     hcat0, 256, hcat0 + 128, 256, N);
    // h1 = relu(bn0([h0|n0] @ [Ws0;Wn0] + bs0)) -> hcat1[:,0:256]
    gemm64<1><<<dim3(4, gby), 256, 0, stream>>>(
        hcat0, 256, hcat0, 256, 256,
        Ws0, Wn0, 128, 256, N, 256, sc0, sh0, hcat1, 512);
    // n1 = mean-neighbor(h1) -> hcat1[:,256:512]
    agg_gather<256><<<(N + 3) / 4, 256, 0, stream>>>(off, csr, inv,
                                                     hcat1, 512, hcat1 + 256, 512, N);
    // h2 = relu(bn1([h1|n1] @ [Ws1;Wn1] + bs1))
    gemm64<1><<<dim3(2, gby), 256, 0, stream>>>(
        hcat1, 512, hcat1, 512, 512,
        Ws1, Wn1, 256, 128, N, 512, sc1, sh1, h2, 128);
    // hf = relu([h0|h2] @ Wr + br)
    gemm64<1><<<dim3(2, gby), 256, 0, stream>>>(
        hcat0, 256, h2, 128, 128,
        Wr, Wr, 256, 128, N, 256, sc_r, sh_r, hf, 128);
    // tc = relu(hf @ Wc1 + bc1)
    gemm64<1><<<dim3(1, gby), 256, 0, stream>>>(
        hf, 128, hf, 128, 128,
        Wc1, Wc1, 128, 64, N, 128, sc_c1, sh_c1, tc, 64);
    // out = tc @ Wc2 + bc2 (f32)
    gemm16_f32<<<dim3(1, N / 16), dim3(16, 16), 0, stream>>>(
        tc, 64, Wc2, 16, 64, sc_c2, sh_c2, out);
}

// Round 10
// 501.708 us; speedup vs baseline: 7.6885x; 1.6992x over previous
//
#include <hip/hip_runtime.h>

typedef short v8s __attribute__((ext_vector_type(8)));
typedef float v4f __attribute__((ext_vector_type(4)));
typedef unsigned short u16;
typedef unsigned int u32;

#define NNODES 50000
#define NEDGES 800000
#define SCAN_NB 49  // ceil(50000/1024)

__device__ __forceinline__ float bf2f(u16 b) {
    u32 u = ((u32)b) << 16;
    return __builtin_bit_cast(float, u);
}
__device__ __forceinline__ u16 f2bf(float f) {
    u32 u = __builtin_bit_cast(u32, f);
    u32 r = (u + 0x7fffu + ((u >> 16) & 1u)) >> 16;
    return (u16)r;
}

// ---------------- features f32 -> bf16 ----------------
__global__ __launch_bounds__(256) void cvt_feat(const float* __restrict__ in,
                                                u16* __restrict__ out, int n) {
    int i = (blockIdx.x * 256 + threadIdx.x) * 8;
    if (i >= n) return;
    const float4* f = (const float4*)(in + i);
    float4 v0 = f[0], v1 = f[1];
    uint4 o;
    o.x = (u32)f2bf(v0.x) | ((u32)f2bf(v0.y) << 16);
    o.y = (u32)f2bf(v0.z) | ((u32)f2bf(v0.w) << 16);
    o.z = (u32)f2bf(v1.x) | ((u32)f2bf(v1.y) << 16);
    o.w = (u32)f2bf(v1.z) | ((u32)f2bf(v1.w) << 16);
    *(uint4*)(out + i) = o;
}

// ---------------- CSR build (parallel scan) ----------------
__global__ __launch_bounds__(256) void deg_hist(const int* __restrict__ dst,
                                                int* __restrict__ deg, int E) {
    int e = blockIdx.x * 256 + threadIdx.x;
    if (e < E) atomicAdd(&deg[dst[e]], 1);
}

__global__ __launch_bounds__(1024) void scan_blk(const int* __restrict__ deg,
                                                 int* __restrict__ off,
                                                 int* __restrict__ part, int n) {
    __shared__ int lds[1024];
    int t = threadIdx.x;
    int i = blockIdx.x * 1024 + t;
    int v = (i < n) ? deg[i] : 0;
    lds[t] = v;
    __syncthreads();
    for (int o = 1; o < 1024; o <<= 1) {
        int x = (t >= o) ? lds[t - o] : 0;
        __syncthreads();
        lds[t] += x;
        __syncthreads();
    }
    if (i < n) off[i] = lds[t] - v;  // exclusive
    if (t == 1023) part[blockIdx.x] = lds[1023];
}

__global__ __launch_bounds__(64) void scan_part(int* __restrict__ part, int nb) {
    __shared__ int lds[64];
    int t = threadIdx.x;
    int v = (t < nb) ? part[t] : 0;
    lds[t] = v;
    __syncthreads();
    for (int o = 1; o < 64; o <<= 1) {
        int x = (t >= o) ? lds[t - o] : 0;
        __syncthreads();
        lds[t] += x;
        __syncthreads();
    }
    if (t < nb) part[t] = lds[t] - v;  // exclusive
}

__global__ __launch_bounds__(1024) void scan_add(const int* __restrict__ deg,
                                                 int* __restrict__ off,
                                                 int* __restrict__ cursor,
                                                 float* __restrict__ inv,
                                                 const int* __restrict__ part, int n) {
    int i = blockIdx.x * 1024 + threadIdx.x;
    if (i < n) {
        int o = off[i] + part[blockIdx.x];
        off[i] = o;
        cursor[i] = o;
        int d = deg[i];
        inv[i] = 1.0f / (float)(d > 0 ? d : 1);
    }
    if (i == 0) off[n] = NEDGES;
}

__global__ __launch_bounds__(256) void csr_fill(const int* __restrict__ src,
                                                const int* __restrict__ dst,
                                                int* __restrict__ cursor,
                                                int* __restrict__ csr, int E) {
    int e = blockIdx.x * 256 + threadIdx.x;
    if (e < E) {
        int p = atomicAdd(&cursor[dst[e]], 1);
        csr[p] = src[e];
    }
}

// ---------------- weight packing f32 -> bf16 MFMA B-fragments -------------
// packed elem idx = frag*512 + lane*8 + j ; frag = kt*(N/16)+nt
// k = kt*32 + (lane>>4)*8 + j ; col = nt*16 + (lane&15) ; B row-major [K1+K2, N]
__global__ __launch_bounds__(256) void pack_b(const float* __restrict__ B1, int K1,
                                              const float* __restrict__ B2, int K2,
                                              int N, u16* __restrict__ out) {
    int tid = blockIdx.x * 256 + threadIdx.x;
    int total = (K1 + K2) * N;
    if (tid >= total) return;
    int frag = tid >> 9;
    int rem = tid & 511;
    int lane = rem >> 3;
    int j = rem & 7;
    int nf = N >> 4;
    int kt = frag / nf, nt = frag - kt * nf;
    int k = kt * 32 + (lane >> 4) * 8 + j;
    int n = nt * 16 + (lane & 15);
    float v = (k < K1) ? B1[(size_t)k * N + n] : B2[(size_t)(k - K1) * N + n];
    out[tid] = f2bf(v);
}

// ---------------- epilogue params ----------------
__global__ __launch_bounds__(256) void prep_epi(
    const float* b_in, const float* bs0, const float* g0, const float* bt0,
    const float* m0, const float* v0,
    const float* bs1, const float* g1, const float* bt1, const float* m1, const float* v1,
    const float* br, const float* bc1, const float* bc2,
    float* sc_in, float* sh_in, float* sc0, float* sh0, float* sc1, float* sh1,
    float* sc_r, float* sh_r, float* sc_c1, float* sh_c1, float* sc_c2, float* sh_c2) {
    int t = threadIdx.x;
    if (t < 128) { sc_in[t] = 1.f; sh_in[t] = b_in[t]; }
    if (t < 256) {
        float s = g0[t] * rsqrtf(v0[t] + 1e-5f);
        sc0[t] = s;
        sh0[t] = (bs0[t] - m0[t]) * s + bt0[t];
    }
    if (t < 128) {
        float s = g1[t] * rsqrtf(v1[t] + 1e-5f);
        sc1[t] = s;
        sh1[t] = (bs1[t] - m1[t]) * s + bt1[t];
    }
    if (t < 128) { sc_r[t] = 1.f; sh_r[t] = br[t]; }
    if (t < 64)  { sc_c1[t] = 1.f; sh_c1[t] = bc1[t]; }
    if (t < 16)  { sc_c2[t] = 1.f; sh_c2[t] = bc2[t]; }
}

// ---------------- MFMA bf16 GEMM: C = act((A0|A1)@B * scale + shift) ------
// A split along K at kt boundary kt_split. A bf16 row-major; B packed frags.
// block = 256 = 4 waves; wave computes 32 rows x BN cols. grid (M+127)/128.
template <int BN, bool RELU, bool F32OUT>
__global__ __launch_bounds__(256) void gemm_bf16(
    const u16* __restrict__ A0, int lda0,
    const u16* __restrict__ A1, int lda1, int kt_split,
    int M, int K,
    const v8s* __restrict__ Bp,
    const float* __restrict__ scale, const float* __restrict__ shift,
    u16* __restrict__ C, float* __restrict__ Cf, int ldc) {
    constexpr int NF = BN / 16;
    int lane = threadIdx.x & 63;
    int wave = threadIdx.x >> 6;
    int quad = lane >> 4;
    int l16 = lane & 15;
    int base = blockIdx.x * 128 + wave * 32;

    v4f acc[2][NF];
#pragma unroll
    for (int rg = 0; rg < 2; rg++)
#pragma unroll
        for (int nt = 0; nt < NF; nt++) acc[rg][nt] = (v4f)0.0f;

    int r0 = base + l16;       if (r0 > M - 1) r0 = M - 1;
    int r1 = base + 16 + l16;  if (r1 > M - 1) r1 = M - 1;
    const u16* a00 = A0 + (size_t)r0 * lda0 + quad * 8;
    const u16* a10 = A0 + (size_t)r1 * lda0 + quad * 8;
    const u16* a01 = A1 + (size_t)r0 * lda1 + quad * 8;
    const u16* a11 = A1 + (size_t)r1 * lda1 + quad * 8;

    int ktn = K >> 5;
    for (int kt = 0; kt < ktn; kt++) {
        const u16 *p0, *p1;
        if (kt < kt_split) {
            p0 = a00 + kt * 32;
            p1 = a10 + kt * 32;
        } else {
            p0 = a01 + (kt - kt_split) * 32;
            p1 = a11 + (kt - kt_split) * 32;
        }
        v8s a0 = *(const v8s*)p0;
        v8s a1 = *(const v8s*)p1;
        const v8s* bb = Bp + (size_t)kt * NF * 64 + lane;
#pragma unroll
        for (int nt = 0; nt < NF; nt++) {
            v8s b = bb[nt * 64];
            acc[0][nt] = __builtin_amdgcn_mfma_f32_16x16x32_bf16(a0, b, acc[0][nt], 0, 0, 0);
            acc[1][nt] = __builtin_amdgcn_mfma_f32_16x16x32_bf16(a1, b, acc[1][nt], 0, 0, 0);
        }
    }

#pragma unroll
    for (int rg = 0; rg < 2; rg++) {
        int rbase = base + rg * 16 + quad * 4;
#pragma unroll
        for (int nt = 0; nt < NF; nt++) {
            int col = nt * 16 + l16;
            float s = scale[col], sh = shift[col];
#pragma unroll
            for (int i = 0; i < 4; i++) {
                int row = rbase + i;
                if (row < M) {
                    float v = acc[rg][nt][i] * s + sh;
                    if (RELU) v = v > 0.f ? v : 0.f;
                    if (F32OUT) Cf[(size_t)row * ldc + col] = v;
                    else C[(size_t)row * ldc + col] = f2bf(v);
                }
            }
        }
    }
}

// ---------------- CSR gather mean, bf16 in/out, f32 accum -----------------
template <int F>
__global__ __launch_bounds__(256) void agg_gather(
    const int* __restrict__ off, const int* __restrict__ csr,
    const float* __restrict__ inv_deg,
    const u16* __restrict__ H, int ldh,
    u16* __restrict__ D, int ldd, int n) {
    int v = blockIdx.x * 4 + (threadIdx.x >> 6);
    if (v >= n) return;
    int lane = threadIdx.x & 63;
    int e0 = off[v], e1 = off[v + 1];
    float s = inv_deg[v];
    if constexpr (F == 128) {
        float a0 = 0.f, a1 = 0.f;
        for (int e = e0; e < e1; e++) {
            int u = csr[e];
            u32 w = *(const u32*)(H + (size_t)u * ldh + lane * 2);
            a0 += bf2f((u16)w);
            a1 += bf2f((u16)(w >> 16));
        }
        u32 o = (u32)f2bf(a0 * s) | ((u32)f2bf(a1 * s) << 16);
        *(u32*)(D + (size_t)v * ldd + lane * 2) = o;
    } else {
        float a0 = 0.f, a1 = 0.f, a2 = 0.f, a3 = 0.f;
        for (int e = e0; e < e1; e++) {
            int u = csr[e];
            uint2 w = *(const uint2*)(H + (size_t)u * ldh + lane * 4);
            a0 += bf2f((u16)w.x);
            a1 += bf2f((u16)(w.x >> 16));
            a2 += bf2f((u16)w.y);
            a3 += bf2f((u16)(w.y >> 16));
        }
        uint2 o;
        o.x = (u32)f2bf(a0 * s) | ((u32)f2bf(a1 * s) << 16);
        o.y = (u32)f2bf(a2 * s) | ((u32)f2bf(a3 * s) << 16);
        *(uint2*)(D + (size_t)v * ldd + lane * 4) = o;
    }
}

// ---------------- launch ----------------
extern "C" void kernel_launch(void* const* d_in, const int* in_sizes, int n_in,
                              void* d_out, int out_size, void* d_ws, size_t ws_size,
                              hipStream_t stream) {
    const int N = NNODES, E = NEDGES;
    const float* features = (const float*)d_in[0];
    const int* src = (const int*)d_in[1];
    const int* dst = (const int*)d_in[2];
    float* out = (float*)d_out;  // f32 output (R7 probe)

    char* w = (char*)d_ws;
    auto alloc = [&](size_t bytes) -> char* {
        char* p = w;
        w += (bytes + 255) & ~(size_t)255;
        return p;
    };
    int*   deg    = (int*)alloc((size_t)N * 4);
    int*   off    = (int*)alloc((size_t)(N + 1) * 4);
    int*   cursor = (int*)alloc((size_t)N * 4);
    int*   csr    = (int*)alloc((size_t)E * 4);
    int*   part   = (int*)alloc(64 * 4);
    float* inv    = (float*)alloc((size_t)N * 4);
    u16*   fb     = (u16*)alloc((size_t)N * 128 * 2);  // features bf16; later h2
    u16*   hcat0  = (u16*)alloc((size_t)N * 256 * 2);  // [h0 | n0]
    u16*   hcat1  = (u16*)alloc((size_t)N * 512 * 2);  // [h1 | n1]; later hf,tc
    u16*   Winp   = (u16*)alloc(128 * 128 * 2);
    u16*   Wc0p   = (u16*)alloc(256 * 256 * 2);
    u16*   Wc1p   = (u16*)alloc(512 * 128 * 2);
    u16*   Wrp    = (u16*)alloc(256 * 128 * 2);
    u16*   Wm1p   = (u16*)alloc(128 * 64 * 2);
    u16*   Wm2p   = (u16*)alloc(64 * 16 * 2);
    float* sc_in = (float*)alloc(128 * 4); float* sh_in = (float*)alloc(128 * 4);
    float* sc0   = (float*)alloc(256 * 4); float* sh0   = (float*)alloc(256 * 4);
    float* sc1   = (float*)alloc(128 * 4); float* sh1   = (float*)alloc(128 * 4);
    float* sc_r  = (float*)alloc(128 * 4); float* sh_r  = (float*)alloc(128 * 4);
    float* sc_c1 = (float*)alloc(64 * 4);  float* sh_c1 = (float*)alloc(64 * 4);
    float* sc_c2 = (float*)alloc(16 * 4);  float* sh_c2 = (float*)alloc(16 * 4);
    u16* h2 = fb;                          // fb dead after h0 gemm
    u16* hf = hcat1;                       // hcat1 dead after h2 gemm
    u16* tc = hcat1 + (size_t)N * 128;

    hipMemsetAsync(deg, 0, (size_t)N * 4, stream);
    prep_epi<<<1, 256, 0, stream>>>((const float*)d_in[4], (const float*)d_in[7],
                                    (const float*)d_in[8], (const float*)d_in[9],
                                    (const float*)d_in[10], (const float*)d_in[11],
                                    (const float*)d_in[14], (const float*)d_in[15],
                                    (const float*)d_in[16], (const float*)d_in[17],
                                    (const float*)d_in[18], (const float*)d_in[20],
                                    (const float*)d_in[22], (const float*)d_in[24],
                                    sc_in, sh_in, sc0, sh0, sc1, sh1,
                                    sc_r, sh_r, sc_c1, sh_c1, sc_c2, sh_c2);
    cvt_feat<<<(N * 128 / 8 + 255) / 256, 256, 0, stream>>>(features, fb, N * 128);
    pack_b<<<(128 * 128 + 255) / 256, 256, 0, stream>>>(
        (const float*)d_in[3], 128, nullptr, 0, 128, Winp);
    pack_b<<<(256 * 256 + 255) / 256, 256, 0, stream>>>(
        (const float*)d_in[5], 128, (const float*)d_in[6], 128, 256, Wc0p);
    pack_b<<<(512 * 128 + 255) / 256, 256, 0, stream>>>(
        (const float*)d_in[12], 256, (const float*)d_in[13], 256, 128, Wc1p);
    pack_b<<<(256 * 128 + 255) / 256, 256, 0, stream>>>(
        (const float*)d_in[19], 256, nullptr, 0, 128, Wrp);
    pack_b<<<(128 * 64 + 255) / 256, 256, 0, stream>>>(
        (const float*)d_in[21], 128, nullptr, 0, 64, Wm1p);
    pack_b<<<(64 * 16 + 255) / 256, 256, 0, stream>>>(
        (const float*)d_in[23], 64, nullptr, 0, 16, Wm2p);

    deg_hist<<<(E + 255) / 256, 256, 0, stream>>>(dst, deg, E);
    scan_blk<<<SCAN_NB, 1024, 0, stream>>>(deg, off, part, N);
    scan_part<<<1, 64, 0, stream>>>(part, SCAN_NB);
    scan_add<<<SCAN_NB, 1024, 0, stream>>>(deg, off, cursor, inv, part, N);
    csr_fill<<<(E + 255) / 256, 256, 0, stream>>>(src, dst, cursor, csr, E);

    int gb = (N + 127) / 128;
    // h0 = relu(features @ W_in + b_in) -> hcat0[:,0:128]
    gemm_bf16<128, true, false><<<gb, 256, 0, stream>>>(
        fb, 128, fb, 128, 4, N, 128, (const v8s*)Winp, sc_in, sh_in,
        hcat0, nullptr, 256);
    // n0 -> hcat0[:,128:256]
    agg_gather<128><<<(N + 3) / 4, 256, 0, stream>>>(off, csr, inv,
                                                     hcat0, 256, hcat0 + 128, 256, N);
    // h1 = relu(bn0(hcat0 @ [Ws0;Wn0] + bs0)) -> hcat1[:,0:256]
    gemm_bf16<256, true, false><<<gb, 256, 0, stream>>>(
        hcat0, 256, hcat0, 256, 8, N, 256, (const v8s*)Wc0p, sc0, sh0,
        hcat1, nullptr, 512);
    // n1 -> hcat1[:,256:512]
    agg_gather<256><<<(N + 3) / 4, 256, 0, stream>>>(off, csr, inv,
                                                     hcat1, 512, hcat1 + 256, 512, N);
    // h2 = relu(bn1(hcat1 @ [Ws1;Wn1] + bs1)) -> h2 (=fb)
    gemm_bf16<128, true, false><<<gb, 256, 0, stream>>>(
        hcat1, 512, hcat1, 512, 16, N, 512, (const v8s*)Wc1p, sc1, sh1,
        h2, nullptr, 128);
    // hf = relu([h0|h2] @ Wr + br)
    gemm_bf16<128, true, false><<<gb, 256, 0, stream>>>(
        hcat0, 256, h2, 128, 4, N, 256, (const v8s*)Wrp, sc_r, sh_r,
        hf, nullptr, 128);
    // tc = relu(hf @ Wc1 + bc1)
    gemm_bf16<64, true, false><<<gb, 256, 0, stream>>>(
        hf, 128, hf, 128, 4, N, 128, (const v8s*)Wm1p, sc_c1, sh_c1,
        tc, nullptr, 64);
    // out = tc @ Wc2 + bc2 (f32)
    gemm_bf16<16, false, true><<<gb, 256, 0, stream>>>(
        tc, 64, tc, 64, 2, N, 64, (const v8s*)Wm2p, sc_c2, sh_c2,
        nullptr, out, 16);
}